// Round 4
// baseline (276.653 us; speedup 1.0000x reference)
//
#include <hip/hip_runtime.h>

#define HD 1024
#define FD 2816
#define NE 8
#define NT 1024
#define NSLOT (NT * 2)

typedef short short8 __attribute__((ext_vector_type(8)));
typedef short short4v __attribute__((ext_vector_type(4)));
typedef float f32x4 __attribute__((ext_vector_type(4)));
typedef float f32x2 __attribute__((ext_vector_type(2)));

typedef __attribute__((address_space(3))) unsigned lds_u32;
typedef __attribute__((address_space(1))) const unsigned glb_u32;

__device__ __forceinline__ void glds16(const void* g, void* l) {
  __builtin_amdgcn_global_load_lds((glb_u32*)g, (lds_u32*)l, 16, 0, 0);
}

__device__ __forceinline__ short f2bf(float f) {
  unsigned u = __builtin_bit_cast(unsigned, f);
  u += 0x7FFFu + ((u >> 16) & 1u);   // round-to-nearest-even
  return (short)(u >> 16);
}
__device__ __forceinline__ int imin(int a, int b) { return a < b ? a : b; }

// ---------------- router ----------------------------------------------------
__global__ void router_kernel(const float* __restrict__ x,
                              const float* __restrict__ rw,
                              int* __restrict__ counts,
                              int* __restrict__ tok_i,
                              float* __restrict__ tok_w) {
  const int t = blockIdx.x;
  const int lane = threadIdx.x;
  const float* px = x + (size_t)t * HD;
  float acc[NE];
#pragma unroll
  for (int e = 0; e < NE; e++) acc[e] = 0.f;
  for (int h = lane; h < HD; h += 64) {
    float xv = px[h];
#pragma unroll
    for (int e = 0; e < NE; e++) acc[e] += xv * rw[e * HD + h];
  }
#pragma unroll
  for (int e = 0; e < NE; e++) {
#pragma unroll
    for (int off = 32; off > 0; off >>= 1)
      acc[e] += __shfl_xor(acc[e], off, 64);
  }
  if (lane == 0) {
    float mx = acc[0];
#pragma unroll
    for (int e = 1; e < NE; e++) mx = fmaxf(mx, acc[e]);
    float ex[NE];
#pragma unroll
    for (int e = 0; e < NE; e++) ex[e] = __expf(acc[e] - mx);
    int i1 = 0;
#pragma unroll
    for (int e = 1; e < NE; e++) if (ex[e] > ex[i1]) i1 = e;
    int i2 = (i1 == 0) ? 1 : 0;
#pragma unroll
    for (int e = 0; e < NE; e++) if (e != i1 && ex[e] > ex[i2]) i2 = e;
    float inv = 1.f / (ex[i1] + ex[i2]);
    tok_i[t * 2 + 0] = i1; tok_w[t * 2 + 0] = ex[i1] * inv;
    tok_i[t * 2 + 1] = i2; tok_w[t * 2 + 1] = ex[i2] * inv;
    atomicAdd(&counts[i1], 1);
    atomicAdd(&counts[i2], 1);
  }
}

// ---------------- scan ------------------------------------------------------
__global__ void scan_kernel(const int* __restrict__ counts,
                            int* __restrict__ bases,
                            int* __restrict__ cursor) {
  if (threadIdx.x == 0) {
    int s = 0;
    for (int e = 0; e < NE; e++) { bases[e] = s; cursor[e] = s; s += counts[e]; }
    bases[NE] = s;
  }
}

// ---------------- fill ------------------------------------------------------
__global__ void fill_kernel(const int* __restrict__ tok_i,
                            const float* __restrict__ tok_w,
                            int* __restrict__ cursor,
                            int* __restrict__ slot_token,
                            float* __restrict__ slot_w,
                            int* __restrict__ slot_of) {
  int t = blockIdx.x * 256 + threadIdx.x;
  if (t >= NT) return;
#pragma unroll
  for (int k = 0; k < 2; k++) {
    int e = tok_i[t * 2 + k];
    int pos = atomicAdd(&cursor[e], 1);
    slot_token[pos] = t;
    slot_w[pos] = tok_w[t * 2 + k];
    slot_of[t * 2 + k] = pos;
  }
}

// ---------------- gather x -> bf16 xg (linear) ------------------------------
__global__ void gather_kernel(const float* __restrict__ x,
                              const int* __restrict__ slot_token,
                              short* __restrict__ xg) {
  const int slot = blockIdx.x;
  const int tok = slot_token[slot];
  const int t = threadIdx.x;
  f32x4 v = *(const f32x4*)(x + (size_t)tok * HD + t * 4);
  short4v s;
#pragma unroll
  for (int j = 0; j < 4; j++) s[j] = f2bf(v[j]);
  *(short4v*)&xg[(size_t)slot * HD + t * 4] = s;
}

// Pair-line LDS layout: rows r stored 2 per 128B line p=r>>1; 16B chunk c of
// row r sits at slot j = ((r&1)<<2 | c) ^ (p&7). 2-way on write and read.

// ---------------- gate+up grouped GEMM (BM=128 BN=64x2 BK=32) ---------------
// grid: (44, 16, 8), block 256 (4 waves 2m x 2n; wave 64x32 per mat)
__global__ __launch_bounds__(256, 2) void gateup_kernel(
    const short* __restrict__ xg, const float* __restrict__ gate_w,
    const float* __restrict__ up_w, const int* __restrict__ bases,
    short* __restrict__ m_out) {
  const int e = blockIdx.z;
  const int b0 = bases[e];
  const int ne = bases[e + 1] - b0;
  const int row0 = blockIdx.y * 128;
  if (row0 >= ne) return;
  const int n0 = blockIdx.x * 64;

  __shared__ short As[2][128 * 32];
  __shared__ short Bs[2][2][64 * 32];

  const int tid = threadIdx.x;
  const int lane = tid & 63, wid = tid >> 6;
  const int l15 = lane & 15, l4 = lane >> 4;
  const int wm = wid >> 1, wn = wid & 1;

  // A staging: 512 chunks/tile, 2 per thread; inverse-swizzled sources
  const short* asrc[2];
#pragma unroll
  for (int j = 0; j < 2; j++) {
    int i = j * 256 + tid;
    int p = i >> 3;
    int v = (i & 7) ^ (p & 7);
    int rl = 2 * p + (v >> 2), c = v & 3;
    int slot = b0 + imin(row0 + rl, ne - 1);
    asrc[j] = xg + (size_t)slot * HD + c * 8;
  }

  // B staging: mat per half-block; thread owns 2 f x 8 k
  const int mat = tid >> 7;
  const int rb = tid & 127;
  const int fp = rb & 31, kq = rb >> 5;   // kq in 0..3
  const float* wsel = (mat ? up_w : gate_w) + (size_t)e * HD * FD + n0 + fp * 2;

  f32x4 accG[4][2], accU[4][2];
#pragma unroll
  for (int mi = 0; mi < 4; mi++)
#pragma unroll
    for (int ni = 0; ni < 2; ni++) { accG[mi][ni] = (f32x4)0.f; accU[mi][ni] = (f32x4)0.f; }

  f32x2 bv[8];

  auto stageA = [&](int buf, int k0) {
#pragma unroll
    for (int j = 0; j < 2; j++)
      glds16(asrc[j] + k0, &As[buf][j * 2048 + wid * 512]);
  };
  auto loadB = [&](int k0) {
#pragma unroll
    for (int i = 0; i < 8; i++)
      bv[i] = *(const f32x2*)(wsel + (size_t)(k0 + kq * 8 + i) * FD);
  };
  auto writeB = [&](int buf) {
    short* Bd = &Bs[buf][mat][0];
#pragma unroll
    for (int ff = 0; ff < 2; ff++) {
      int jslot = ((ff << 2) | kq) ^ (fp & 7);
      short8 s;
#pragma unroll
      for (int i = 0; i < 8; i++) s[i] = f2bf(bv[i][ff]);
      *(short8*)&Bd[fp * 64 + jslot * 8] = s;
    }
  };

  const int NTL = HD / 32;   // 32
  stageA(0, 0); loadB(0); writeB(0);
  stageA(1, 32); loadB(32);
  __syncthreads();

  for (int t = 0; t < NTL; t++) {
    const int cur = t & 1;
    short8 a[4], bg[2], bu[2];
#pragma unroll
    for (int mi = 0; mi < 4; mi++) {
      int R = wm * 64 + mi * 16 + l15;
      a[mi] = *(const short8*)&As[cur][(R >> 1) * 64 +
                ((((R & 1) << 2) | l4) ^ ((R >> 1) & 7)) * 8];
    }
#pragma unroll
    for (int ni = 0; ni < 2; ni++) {
      int n = wn * 32 + ni * 16 + l15;
      int off = (n >> 1) * 64 + ((((n & 1) << 2) | l4) ^ ((n >> 1) & 7)) * 8;
      bg[ni] = *(const short8*)&Bs[cur][0][off];
      bu[ni] = *(const short8*)&Bs[cur][1][off];
    }
#pragma unroll
    for (int mi = 0; mi < 4; mi++)
#pragma unroll
      for (int ni = 0; ni < 2; ni++) {
        accG[mi][ni] = __builtin_amdgcn_mfma_f32_16x16x32_bf16(a[mi], bg[ni], accG[mi][ni], 0, 0, 0);
        accU[mi][ni] = __builtin_amdgcn_mfma_f32_16x16x32_bf16(a[mi], bu[ni], accU[mi][ni], 0, 0, 0);
      }
    if (t + 1 < NTL) writeB(cur ^ 1);
    __syncthreads();
    if (t + 2 < NTL) { stageA(cur, (t + 2) * 32); loadB((t + 2) * 32); }
  }

#pragma unroll
  for (int mi = 0; mi < 4; mi++)
#pragma unroll
    for (int ni = 0; ni < 2; ni++)
#pragma unroll
      for (int rr = 0; rr < 4; rr++) {
        int row = row0 + wm * 64 + mi * 16 + l4 * 4 + rr;
        if (row < ne) {
          int slot = b0 + row;
          float g = accG[mi][ni][rr];
          float u = accU[mi][ni][rr];
          float mv = (g / (1.f + __expf(-g))) * u;
          m_out[(size_t)slot * FD + n0 + wn * 32 + ni * 16 + l15] = f2bf(mv);
        }
      }
}

// ---------------- down grouped GEMM (BM=64 BN=64 BK=32) ---------------------
// grid: (16, 32, 8), block 256 (4 waves 2m x 2n; wave 32x32)
__global__ __launch_bounds__(256, 2) void down_kernel(
    const short* __restrict__ m_in, const float* __restrict__ down_w,
    const int* __restrict__ bases, const float* __restrict__ slot_w,
    float* __restrict__ out_slot) {
  const int e = blockIdx.z;
  const int b0 = bases[e];
  const int ne = bases[e + 1] - b0;
  const int row0 = blockIdx.y * 64;
  if (row0 >= ne) return;
  const int n0 = blockIdx.x * 64;

  __shared__ short As[2][64 * 32];
  __shared__ short Bs[2][64 * 32];

  const int tid = threadIdx.x;
  const int lane = tid & 63, wid = tid >> 6;
  const int l15 = lane & 15, l4 = lane >> 4;
  const int wm = wid >> 1, wn = wid & 1;

  // A: 256 chunks/tile, 1 per thread
  const short* asrc;
  {
    int p = tid >> 3;
    int v = (tid & 7) ^ (p & 7);
    int rl = 2 * p + (v >> 2), c = v & 3;
    int slot = b0 + imin(row0 + rl, ne - 1);
    asrc = m_in + (size_t)slot * FD + c * 8;
  }

  // B: tid<128 stage; thread owns 2 h x 8 k
  const int rb = tid & 127;
  const int fp = rb & 31, kq = rb >> 5;
  const float* wb = down_w + (size_t)e * FD * HD + n0 + fp * 2;

  f32x4 acc[2][2];
#pragma unroll
  for (int mi = 0; mi < 2; mi++)
#pragma unroll
    for (int ni = 0; ni < 2; ni++) acc[mi][ni] = (f32x4)0.f;

  f32x2 bv[8];

  auto stageA = [&](int buf, int k0) {
    glds16(asrc + k0, &As[buf][wid * 512]);
  };
  auto loadB = [&](int k0) {
    if (tid < 128) {
#pragma unroll
      for (int i = 0; i < 8; i++)
        bv[i] = *(const f32x2*)(wb + (size_t)(k0 + kq * 8 + i) * HD);
    }
  };
  auto writeB = [&](int buf) {
    if (tid < 128) {
#pragma unroll
      for (int ff = 0; ff < 2; ff++) {
        int jslot = ((ff << 2) | kq) ^ (fp & 7);
        short8 s;
#pragma unroll
        for (int i = 0; i < 8; i++) s[i] = f2bf(bv[i][ff]);
        *(short8*)&Bs[buf][fp * 64 + jslot * 8] = s;
      }
    }
  };

  const int NTL = FD / 32;   // 88
  stageA(0, 0); loadB(0); writeB(0);
  stageA(1, 32); loadB(32);
  __syncthreads();

  for (int t = 0; t < NTL; t++) {
    const int cur = t & 1;
    short8 a[2], bf[2];
#pragma unroll
    for (int mi = 0; mi < 2; mi++) {
      int R = wm * 32 + mi * 16 + l15;
      a[mi] = *(const short8*)&As[cur][(R >> 1) * 64 +
                ((((R & 1) << 2) | l4) ^ ((R >> 1) & 7)) * 8];
    }
#pragma unroll
    for (int ni = 0; ni < 2; ni++) {
      int n = wn * 32 + ni * 16 + l15;
      bf[ni] = *(const short8*)&Bs[cur][(n >> 1) * 64 +
                ((((n & 1) << 2) | l4) ^ ((n >> 1) & 7)) * 8];
    }
#pragma unroll
    for (int mi = 0; mi < 2; mi++)
#pragma unroll
      for (int ni = 0; ni < 2; ni++)
        acc[mi][ni] = __builtin_amdgcn_mfma_f32_16x16x32_bf16(a[mi], bf[ni], acc[mi][ni], 0, 0, 0);
    if (t + 1 < NTL) writeB(cur ^ 1);
    __syncthreads();
    if (t + 2 < NTL) { stageA(cur, (t + 2) * 32); loadB((t + 2) * 32); }
  }

#pragma unroll
  for (int mi = 0; mi < 2; mi++)
#pragma unroll
    for (int ni = 0; ni < 2; ni++)
#pragma unroll
      for (int rr = 0; rr < 4; rr++) {
        int row = row0 + wm * 32 + mi * 16 + l4 * 4 + rr;
        if (row < ne) {
          int slot = b0 + row;
          out_slot[(size_t)slot * HD + n0 + wn * 32 + ni * 16 + l15] =
              acc[mi][ni][rr] * slot_w[slot];
        }
      }
}

// ---------------- combine ---------------------------------------------------
__global__ void combine_kernel(const float* __restrict__ out_slot,
                               const int* __restrict__ slot_of,
                               float* __restrict__ out) {
  const int t = blockIdx.x;
  const int s0 = slot_of[t * 2];
  const int s1 = slot_of[t * 2 + 1];
  const int i = threadIdx.x * 4;
  f32x4 a = *(const f32x4*)(out_slot + (size_t)s0 * HD + i);
  f32x4 b = *(const f32x4*)(out_slot + (size_t)s1 * HD + i);
  f32x4 c = a + b;
  *(f32x4*)(out + (size_t)t * HD + i) = c;
}

extern "C" void kernel_launch(void* const* d_in, const int* in_sizes, int n_in,
                              void* d_out, int out_size, void* d_ws,
                              size_t ws_size, hipStream_t stream) {
  const float* x = (const float*)d_in[0];
  const float* rw = (const float*)d_in[1];
  const float* gw = (const float*)d_in[2];
  const float* uw = (const float*)d_in[3];
  const float* dw = (const float*)d_in[4];
  float* out = (float*)d_out;

  char* ws = (char*)d_ws;
  int* counts = (int*)(ws + 0);
  int* cursor = (int*)(ws + 64);
  int* bases = (int*)(ws + 128);
  int* tok_i = (int*)(ws + 256);
  float* tok_w = (float*)(ws + 8448);
  int* slot_token = (int*)(ws + 16640);
  float* slot_w = (float*)(ws + 24832);
  int* slot_of = (int*)(ws + 33024);
  short* xg = (short*)(ws + 41216);               // 2048 x 1024 bf16
  short* m_buf = (short*)(ws + 4235520);          // 2048 x 2816 bf16
  float* out_slot = (float*)(ws + 15769856);      // 2048 x 1024 f32

  hipMemsetAsync(counts, 0, 64, stream);
  router_kernel<<<NT, 64, 0, stream>>>(x, rw, counts, tok_i, tok_w);
  scan_kernel<<<1, 64, 0, stream>>>(counts, bases, cursor);
  fill_kernel<<<NT / 256, 256, 0, stream>>>(tok_i, tok_w, cursor, slot_token,
                                            slot_w, slot_of);
  gather_kernel<<<NSLOT, 256, 0, stream>>>(x, slot_token, xg);
  gateup_kernel<<<dim3(FD / 64, 16, NE), 256, 0, stream>>>(xg, gw, uw, bases,
                                                           m_buf);
  down_kernel<<<dim3(HD / 64, 32, NE), 256, 0, stream>>>(m_buf, dw, bases,
                                                         slot_w, out_slot);
  combine_kernel<<<NT, 256, 0, stream>>>(out_slot, slot_of, out);
}

// Round 5
// 210.402 us; speedup vs baseline: 1.3149x; 1.3149x over previous
//
#include <hip/hip_runtime.h>

#define HD 1024
#define FD 2816
#define NE 8
#define NT 1024
#define NSLOT (NT * 2)
#define NKT (FD / 32)   // 88 down k-tiles

typedef short short8 __attribute__((ext_vector_type(8)));
typedef short short4v __attribute__((ext_vector_type(4)));
typedef float f32x2 __attribute__((ext_vector_type(2)));
typedef float f32x4 __attribute__((ext_vector_type(4)));
typedef float f32x16 __attribute__((ext_vector_type(16)));

typedef __attribute__((address_space(3))) unsigned lds_u32;
typedef __attribute__((address_space(1))) const unsigned glb_u32;

__device__ __forceinline__ void glds16(const void* g, void* l) {
  __builtin_amdgcn_global_load_lds((glb_u32*)g, (lds_u32*)l, 16, 0, 0);
}

__device__ __forceinline__ short f2bf(float f) {
  unsigned u = __builtin_bit_cast(unsigned, f);
  u += 0x7FFFu + ((u >> 16) & 1u);   // round-to-nearest-even
  return (short)(u >> 16);
}
__device__ __forceinline__ int imin(int a, int b) { return a < b ? a : b; }

// ---------------- router ----------------------------------------------------
__global__ void router_kernel(const float* __restrict__ x,
                              const float* __restrict__ rw,
                              int* __restrict__ counts,
                              int* __restrict__ tok_i,
                              float* __restrict__ tok_w) {
  const int t = blockIdx.x;
  const int lane = threadIdx.x;
  const float* px = x + (size_t)t * HD;
  float acc[NE];
#pragma unroll
  for (int e = 0; e < NE; e++) acc[e] = 0.f;
  for (int h = lane; h < HD; h += 64) {
    float xv = px[h];
#pragma unroll
    for (int e = 0; e < NE; e++) acc[e] += xv * rw[e * HD + h];
  }
#pragma unroll
  for (int e = 0; e < NE; e++) {
#pragma unroll
    for (int off = 32; off > 0; off >>= 1)
      acc[e] += __shfl_xor(acc[e], off, 64);
  }
  if (lane == 0) {
    float mx = acc[0];
#pragma unroll
    for (int e = 1; e < NE; e++) mx = fmaxf(mx, acc[e]);
    float ex[NE];
#pragma unroll
    for (int e = 0; e < NE; e++) ex[e] = __expf(acc[e] - mx);
    int i1 = 0;
#pragma unroll
    for (int e = 1; e < NE; e++) if (ex[e] > ex[i1]) i1 = e;
    int i2 = (i1 == 0) ? 1 : 0;
#pragma unroll
    for (int e = 0; e < NE; e++) if (e != i1 && ex[e] > ex[i2]) i2 = e;
    float inv = 1.f / (ex[i1] + ex[i2]);
    tok_i[t * 2 + 0] = i1; tok_w[t * 2 + 0] = ex[i1] * inv;
    tok_i[t * 2 + 1] = i2; tok_w[t * 2 + 1] = ex[i2] * inv;
    atomicAdd(&counts[i1], 1);
    atomicAdd(&counts[i2], 1);
  }
}

// ---------------- scan ------------------------------------------------------
__global__ void scan_kernel(const int* __restrict__ counts,
                            int* __restrict__ bases,
                            int* __restrict__ cursor) {
  if (threadIdx.x == 0) {
    int s = 0;
    for (int e = 0; e < NE; e++) { bases[e] = s; cursor[e] = s; s += counts[e]; }
    bases[NE] = s;
  }
}

// ---------------- fill ------------------------------------------------------
__global__ void fill_kernel(const int* __restrict__ tok_i,
                            const float* __restrict__ tok_w,
                            int* __restrict__ cursor,
                            int* __restrict__ slot_token,
                            float* __restrict__ slot_w,
                            int* __restrict__ slot_of) {
  int t = blockIdx.x * 256 + threadIdx.x;
  if (t >= NT) return;
#pragma unroll
  for (int k = 0; k < 2; k++) {
    int e = tok_i[t * 2 + k];
    int pos = atomicAdd(&cursor[e], 1);
    slot_token[pos] = t;
    slot_w[pos] = tok_w[t * 2 + k];
    slot_of[t * 2 + k] = pos;
  }
}

// ---------------- gather x -> bf16 xg (linear) ------------------------------
__global__ void gather_kernel(const float* __restrict__ x,
                              const int* __restrict__ slot_token,
                              short* __restrict__ xg) {
  const int slot = blockIdx.x;
  const int tok = slot_token[slot];
  const int t = threadIdx.x;
  f32x4 v = *(const f32x4*)(x + (size_t)tok * HD + t * 4);
  short4v s;
#pragma unroll
  for (int j = 0; j < 4; j++) s[j] = f2bf(v[j]);
  *(short4v*)&xg[(size_t)slot * HD + t * 4] = s;
}

// ---------------- pack down_w -> bf16 tiled Pd ------------------------------
// Pd 16B-chunk at [(e*NKT+kt)*512 + p]*8 + j holds column n=2p+((j^(p&7))>>2),
// k = kt*32 + ((j^(p&7))&3)*8 .. +8  (pair-line swizzle baked in).
__global__ __launch_bounds__(256) void pack_down_kernel(
    const float* __restrict__ dw, short* __restrict__ Pd) {
  const int kt = blockIdx.x, e = blockIdx.y;
  const float* src = dw + (size_t)e * FD * HD + (size_t)kt * 32 * HD;
  short* dst = Pd + ((size_t)e * NKT + kt) * 32768;
  __shared__ short L[8192];
  const int tid = threadIdx.x;
  const int pl = tid & 127, kh = tid >> 7;
  for (int w = 0; w < 4; w++) {
    const int nb = w * 256 + pl * 2;
    f32x2 v[16];
#pragma unroll
    for (int i = 0; i < 16; i++)
      v[i] = *(const f32x2*)(src + (size_t)(kh * 16 + i) * HD + nb);
    if (w) __syncthreads();   // prior window's LDS reads done
#pragma unroll
    for (int ff = 0; ff < 2; ff++)
#pragma unroll
      for (int cc = 0; cc < 2; cc++) {
        int c = kh * 2 + cc;
        short8 s;
#pragma unroll
        for (int q = 0; q < 8; q++) s[q] = f2bf(v[cc * 8 + q][ff]);
        int slot = ((ff << 2) | c) ^ (pl & 7);
        *(short8*)&L[pl * 64 + slot * 8] = s;
      }
    __syncthreads();
#pragma unroll
    for (int j = 0; j < 4; j++) {
      short8 s = *(short8*)&L[j * 2048 + tid * 8];
      *(short8*)&dst[(size_t)w * 8192 + j * 2048 + tid * 8] = s;
    }
  }
}

// ---------------- gate+up grouped GEMM (BM=128 BN=64x2 BK=64, 32x32 MFMA) ---
// grid: (44, 16, 8), block 256 (4 waves 2m x 2n; wave 64x32 per mat)
__global__ __launch_bounds__(256, 2) void gateup_kernel(
    const short* __restrict__ xg, const float* __restrict__ gate_w,
    const float* __restrict__ up_w, const int* __restrict__ bases,
    short* __restrict__ m_out) {
  const int e = blockIdx.z;
  const int b0 = bases[e];
  const int ne = bases[e + 1] - b0;
  const int row0 = blockIdx.y * 128;
  if (row0 >= ne) return;
  const int n0 = blockIdx.x * 64;

  __shared__ short As[2][8192];      // [buf][sub*4096 + p*64 + j*8]
  __shared__ short Bs[2][2][4096];   // [buf][mat][sub*2048 + pn*64 + j*8]

  const int tid = threadIdx.x;
  const int lane = tid & 63, wid = tid >> 6;
  const int l31 = lane & 31, l5 = lane >> 5;
  const int wm = wid >> 1, wn = wid & 1;

  // A glds sources: 4 chunks/thread, pair-line xor folded into source addr
  const short* asrc[4];
#pragma unroll
  for (int q = 0; q < 4; q++) {
    int i = q * 256 + tid;
    int sub = i >> 9, ci = i & 511;
    int p = ci >> 3, j = ci & 7;
    int v = j ^ (p & 7);
    int r = 2 * p + (v >> 2), c = v & 3;
    int slot = b0 + imin(row0 + r, ne - 1);
    asrc[q] = xg + (size_t)slot * HD + sub * 32 + c * 8;
  }

  // B register staging: mat per wave-pair, coalesced f32x2 along n
  const int mat = tid >> 7;
  const int rb = tid & 127;
  const int fp = rb & 31, kq = rb >> 5;
  const float* wsel = (mat ? up_w : gate_w) + (size_t)e * HD * FD + n0 + fp * 2;

  f32x16 accG[2], accU[2];
#pragma unroll
  for (int fm = 0; fm < 2; fm++) { accG[fm] = (f32x16)0.f; accU[fm] = (f32x16)0.f; }

  f32x2 bv[2][8];

  auto stageA = [&](int buf, int k0) {
#pragma unroll
    for (int q = 0; q < 4; q++)
      glds16(asrc[q] + k0, &As[buf][(q * 256 + wid * 64) * 8]);
  };
  auto loadB = [&](int k0) {
#pragma unroll
    for (int sub = 0; sub < 2; sub++)
#pragma unroll
      for (int i = 0; i < 8; i++)
        bv[sub][i] = *(const f32x2*)(wsel + (size_t)(k0 + sub * 32 + kq * 8 + i) * FD);
  };
  auto writeB = [&](int buf) {
    short* Bd = &Bs[buf][mat][0];
#pragma unroll
    for (int sub = 0; sub < 2; sub++)
#pragma unroll
      for (int ff = 0; ff < 2; ff++) {
        short8 s;
#pragma unroll
        for (int i = 0; i < 8; i++) s[i] = f2bf(bv[sub][i][ff]);
        int slot = ((ff << 2) | kq) ^ (fp & 7);
        *(short8*)&Bd[sub * 2048 + fp * 64 + slot * 8] = s;
      }
  };

  const int NTL = HD / 64;   // 16
  stageA(0, 0); loadB(0); writeB(0);
  stageA(1, 64); loadB(64);
  __syncthreads();

  for (int t = 0; t < NTL; t++) {
    const int cur = t & 1;
#pragma unroll
    for (int ks = 0; ks < 4; ks++) {
      const int sub = ks >> 1, chi = (ks & 1) * 2 + l5;
      short8 a[2], bg, bu;
#pragma unroll
      for (int fm = 0; fm < 2; fm++) {
        int r = wm * 64 + fm * 32 + l31;
        int p = r >> 1;
        a[fm] = *(const short8*)&As[cur][sub * 4096 + p * 64 +
                  ((((r & 1) << 2) | chi) ^ (p & 7)) * 8];
      }
      {
        int n = wn * 32 + l31;
        int pn = n >> 1;
        int off = sub * 2048 + pn * 64 + ((((n & 1) << 2) | chi) ^ (pn & 7)) * 8;
        bg = *(const short8*)&Bs[cur][0][off];
        bu = *(const short8*)&Bs[cur][1][off];
      }
#pragma unroll
      for (int fm = 0; fm < 2; fm++) {
        accG[fm] = __builtin_amdgcn_mfma_f32_32x32x16_bf16(a[fm], bg, accG[fm], 0, 0, 0);
        accU[fm] = __builtin_amdgcn_mfma_f32_32x32x16_bf16(a[fm], bu, accU[fm], 0, 0, 0);
      }
    }
    if (t + 1 < NTL) writeB(cur ^ 1);
    __syncthreads();
    if (t + 2 < NTL) { stageA(cur, (t + 2) * 64); loadB((t + 2) * 64); }
  }

#pragma unroll
  for (int fm = 0; fm < 2; fm++)
#pragma unroll
    for (int q = 0; q < 16; q++) {
      int r = row0 + wm * 64 + fm * 32 + (q & 3) + 8 * (q >> 2) + 4 * l5;
      if (r < ne) {
        int slot = b0 + r;
        float g = accG[fm][q], u = accU[fm][q];
        float mv = (g / (1.f + __expf(-g))) * u;
        m_out[(size_t)slot * FD + n0 + wn * 32 + l31] = f2bf(mv);
      }
    }
}

// ---------------- down grouped GEMM (BM=64 BN=64 BK=64, all-glds) -----------
// grid: (16, 32, 8), block 256 (4 waves 2m x 2n; wave 32x32)
__global__ __launch_bounds__(256, 4) void down_kernel(
    const short* __restrict__ m_in, const short* __restrict__ Pd,
    const int* __restrict__ bases, const float* __restrict__ slot_w,
    float* __restrict__ out_slot) {
  const int e = blockIdx.z;
  const int b0 = bases[e];
  const int ne = bases[e + 1] - b0;
  const int row0 = blockIdx.y * 64;
  if (row0 >= ne) return;
  const int n0 = blockIdx.x * 64;

  __shared__ short As[2][4096];   // [buf][sub*2048 + p*64 + j*8]
  __shared__ short Bs[2][4096];

  const int tid = threadIdx.x;
  const int lane = tid & 63, wid = tid >> 6;
  const int l31 = lane & 31, l5 = lane >> 5;
  const int wm = wid >> 1, wn = wid & 1;

  const short* asrc[2];
#pragma unroll
  for (int q = 0; q < 2; q++) {
    int i = q * 256 + tid;
    int sub = i >> 8, ci = i & 255;
    int p = ci >> 3, j = ci & 7;
    int v = j ^ (p & 7);
    int r = 2 * p + (v >> 2), c = v & 3;
    int slot = b0 + imin(row0 + r, ne - 1);
    asrc[q] = m_in + (size_t)slot * FD + sub * 32 + c * 8;
  }
  const short* bbase = Pd + (size_t)e * NKT * 32768 + (size_t)n0 * 32;

  f32x16 acc = (f32x16)0.f;

  auto stage = [&](int buf, int t2) {
    const int k0 = t2 * 64, kt0 = t2 * 2;
#pragma unroll
    for (int q = 0; q < 2; q++) {
      int i = q * 256 + tid;
      int sub = i >> 8, ci = i & 255;
      glds16(asrc[q] + k0, &As[buf][(q * 256 + wid * 64) * 8]);
      glds16(bbase + (size_t)(kt0 + sub) * 32768 + ci * 8,
             &Bs[buf][(q * 256 + wid * 64) * 8]);
    }
  };

  const int NTL = FD / 64;   // 44
  stage(0, 0); stage(1, 1);
  __syncthreads();

  for (int t = 0; t < NTL; t++) {
    const int cur = t & 1;
#pragma unroll
    for (int ks = 0; ks < 4; ks++) {
      const int sub = ks >> 1, chi = (ks & 1) * 2 + l5;
      int r = wm * 32 + l31, p = r >> 1;
      short8 a = *(const short8*)&As[cur][sub * 2048 + p * 64 +
                  ((((r & 1) << 2) | chi) ^ (p & 7)) * 8];
      int n = wn * 32 + l31, pn = n >> 1;
      short8 b = *(const short8*)&Bs[cur][sub * 2048 + pn * 64 +
                  ((((n & 1) << 2) | chi) ^ (pn & 7)) * 8];
      acc = __builtin_amdgcn_mfma_f32_32x32x16_bf16(a, b, acc, 0, 0, 0);
    }
    __syncthreads();
    if (t + 2 < NTL) stage(cur, t + 2);
  }

#pragma unroll
  for (int q = 0; q < 16; q++) {
    int r = row0 + wm * 32 + (q & 3) + 8 * (q >> 2) + 4 * l5;
    if (r < ne) {
      int slot = b0 + r;
      out_slot[(size_t)slot * HD + n0 + wn * 32 + l31] = acc[q] * slot_w[slot];
    }
  }
}

// ---------------- combine ---------------------------------------------------
__global__ void combine_kernel(const float* __restrict__ out_slot,
                               const int* __restrict__ slot_of,
                               float* __restrict__ out) {
  const int t = blockIdx.x;
  const int s0 = slot_of[t * 2];
  const int s1 = slot_of[t * 2 + 1];
  const int i = threadIdx.x * 4;
  f32x4 a = *(const f32x4*)(out_slot + (size_t)s0 * HD + i);
  f32x4 b = *(const f32x4*)(out_slot + (size_t)s1 * HD + i);
  f32x4 c = a + b;
  *(f32x4*)(out + (size_t)t * HD + i) = c;
}

extern "C" void kernel_launch(void* const* d_in, const int* in_sizes, int n_in,
                              void* d_out, int out_size, void* d_ws,
                              size_t ws_size, hipStream_t stream) {
  const float* x = (const float*)d_in[0];
  const float* rw = (const float*)d_in[1];
  const float* gw = (const float*)d_in[2];
  const float* uw = (const float*)d_in[3];
  const float* dw = (const float*)d_in[4];
  float* out = (float*)d_out;

  char* ws = (char*)d_ws;
  int* counts = (int*)(ws + 0);
  int* cursor = (int*)(ws + 64);
  int* bases = (int*)(ws + 128);
  int* tok_i = (int*)(ws + 256);
  float* tok_w = (float*)(ws + 8448);
  int* slot_token = (int*)(ws + 16640);
  float* slot_w = (float*)(ws + 24832);
  int* slot_of = (int*)(ws + 33024);
  short* xg = (short*)(ws + 41216);             // 2048 x 1024 bf16
  short* m_buf = (short*)(ws + 4235520);        // 2048 x 2816 bf16
  float* out_slot = (float*)(ws + 15769856);    // 2048 x 1024 f32
  short* Pd = (short*)(ws + 24158464);          // packed down_w bf16, 46.1 MB

  hipMemsetAsync(counts, 0, 64, stream);
  router_kernel<<<NT, 64, 0, stream>>>(x, rw, counts, tok_i, tok_w);
  scan_kernel<<<1, 64, 0, stream>>>(counts, bases, cursor);
  fill_kernel<<<NT / 256, 256, 0, stream>>>(tok_i, tok_w, cursor, slot_token,
                                            slot_w, slot_of);
  gather_kernel<<<NSLOT, 256, 0, stream>>>(x, slot_token, xg);
  pack_down_kernel<<<dim3(NKT, NE), 256, 0, stream>>>(dw, Pd);
  gateup_kernel<<<dim3(FD / 64, 16, NE), 256, 0, stream>>>(xg, gw, uw, bases,
                                                           m_buf);
  down_kernel<<<dim3(HD / 64, 32, NE), 256, 0, stream>>>(m_buf, Pd, bases,
                                                         slot_w, out_slot);
  combine_kernel<<<NT, 256, 0, stream>>>(out_slot, slot_of, out);
}

// Round 6
// 201.303 us; speedup vs baseline: 1.3743x; 1.0452x over previous
//
#include <hip/hip_runtime.h>

#define HD 1024
#define FD 2816
#define NE 8
#define NT 1024
#define NSLOT (NT * 2)
#define NKT (FD / 32)   // 88 down k-tiles

typedef short short8 __attribute__((ext_vector_type(8)));
typedef short short4v __attribute__((ext_vector_type(4)));
typedef float f32x2 __attribute__((ext_vector_type(2)));
typedef float f32x4 __attribute__((ext_vector_type(4)));
typedef float f32x16 __attribute__((ext_vector_type(16)));

typedef __attribute__((address_space(3))) unsigned lds_u32;
typedef __attribute__((address_space(1))) const unsigned glb_u32;

#define WAITV(N) asm volatile("s_waitcnt vmcnt(" #N ") lgkmcnt(0)" ::: "memory")
#define BARRIER() do { __builtin_amdgcn_s_barrier(); __builtin_amdgcn_sched_barrier(0); } while (0)

__device__ __forceinline__ void glds16(const void* g, void* l) {
  __builtin_amdgcn_global_load_lds((glb_u32*)g, (lds_u32*)l, 16, 0, 0);
}

__device__ __forceinline__ short f2bf(float f) {
  unsigned u = __builtin_bit_cast(unsigned, f);
  u += 0x7FFFu + ((u >> 16) & 1u);   // round-to-nearest-even
  return (short)(u >> 16);
}
__device__ __forceinline__ int imin(int a, int b) { return a < b ? a : b; }

// ---------------- router ----------------------------------------------------
__global__ void router_kernel(const float* __restrict__ x,
                              const float* __restrict__ rw,
                              int* __restrict__ counts,
                              int* __restrict__ tok_i,
                              float* __restrict__ tok_w) {
  const int t = blockIdx.x;
  const int lane = threadIdx.x;
  const float* px = x + (size_t)t * HD;
  float acc[NE];
#pragma unroll
  for (int e = 0; e < NE; e++) acc[e] = 0.f;
  for (int h = lane; h < HD; h += 64) {
    float xv = px[h];
#pragma unroll
    for (int e = 0; e < NE; e++) acc[e] += xv * rw[e * HD + h];
  }
#pragma unroll
  for (int e = 0; e < NE; e++) {
#pragma unroll
    for (int off = 32; off > 0; off >>= 1)
      acc[e] += __shfl_xor(acc[e], off, 64);
  }
  if (lane == 0) {
    float mx = acc[0];
#pragma unroll
    for (int e = 1; e < NE; e++) mx = fmaxf(mx, acc[e]);
    float ex[NE];
#pragma unroll
    for (int e = 0; e < NE; e++) ex[e] = __expf(acc[e] - mx);
    int i1 = 0;
#pragma unroll
    for (int e = 1; e < NE; e++) if (ex[e] > ex[i1]) i1 = e;
    int i2 = (i1 == 0) ? 1 : 0;
#pragma unroll
    for (int e = 0; e < NE; e++) if (e != i1 && ex[e] > ex[i2]) i2 = e;
    float inv = 1.f / (ex[i1] + ex[i2]);
    tok_i[t * 2 + 0] = i1; tok_w[t * 2 + 0] = ex[i1] * inv;
    tok_i[t * 2 + 1] = i2; tok_w[t * 2 + 1] = ex[i2] * inv;
    atomicAdd(&counts[i1], 1);
    atomicAdd(&counts[i2], 1);
  }
}

// ---------------- scan ------------------------------------------------------
__global__ void scan_kernel(const int* __restrict__ counts,
                            int* __restrict__ bases,
                            int* __restrict__ cursor) {
  if (threadIdx.x == 0) {
    int s = 0;
    for (int e = 0; e < NE; e++) { bases[e] = s; cursor[e] = s; s += counts[e]; }
    bases[NE] = s;
  }
}

// ---------------- fill ------------------------------------------------------
__global__ void fill_kernel(const int* __restrict__ tok_i,
                            const float* __restrict__ tok_w,
                            int* __restrict__ cursor,
                            int* __restrict__ slot_token,
                            float* __restrict__ slot_w,
                            int* __restrict__ slot_of) {
  int t = blockIdx.x * 256 + threadIdx.x;
  if (t >= NT) return;
#pragma unroll
  for (int k = 0; k < 2; k++) {
    int e = tok_i[t * 2 + k];
    int pos = atomicAdd(&cursor[e], 1);
    slot_token[pos] = t;
    slot_w[pos] = tok_w[t * 2 + k];
    slot_of[t * 2 + k] = pos;
  }
}

// ---------------- gather x -> bf16 xg (linear) ------------------------------
__global__ void gather_kernel(const float* __restrict__ x,
                              const int* __restrict__ slot_token,
                              short* __restrict__ xg) {
  const int slot = blockIdx.x;
  const int tok = slot_token[slot];
  const int t = threadIdx.x;
  f32x4 v = *(const f32x4*)(x + (size_t)tok * HD + t * 4);
  short4v s;
#pragma unroll
  for (int j = 0; j < 4; j++) s[j] = f2bf(v[j]);
  *(short4v*)&xg[(size_t)slot * HD + t * 4] = s;
}

// ---------------- pack down_w -> bf16 tiled Pd ------------------------------
__global__ __launch_bounds__(256) void pack_down_kernel(
    const float* __restrict__ dw, short* __restrict__ Pd) {
  const int kt = blockIdx.x, e = blockIdx.y;
  const float* src = dw + (size_t)e * FD * HD + (size_t)kt * 32 * HD;
  short* dst = Pd + ((size_t)e * NKT + kt) * 32768;
  __shared__ short L[8192];
  const int tid = threadIdx.x;
  const int pl = tid & 127, kh = tid >> 7;
  for (int w = 0; w < 4; w++) {
    const int nb = w * 256 + pl * 2;
    f32x2 v[16];
#pragma unroll
    for (int i = 0; i < 16; i++)
      v[i] = *(const f32x2*)(src + (size_t)(kh * 16 + i) * HD + nb);
    if (w) __syncthreads();
#pragma unroll
    for (int ff = 0; ff < 2; ff++)
#pragma unroll
      for (int cc = 0; cc < 2; cc++) {
        int c = kh * 2 + cc;
        short8 s;
#pragma unroll
        for (int q = 0; q < 8; q++) s[q] = f2bf(v[cc * 8 + q][ff]);
        int slot = ((ff << 2) | c) ^ (pl & 7);
        *(short8*)&L[pl * 64 + slot * 8] = s;
      }
    __syncthreads();
#pragma unroll
    for (int j = 0; j < 4; j++) {
      short8 s = *(short8*)&L[j * 2048 + tid * 8];
      *(short8*)&dst[(size_t)w * 8192 + j * 2048 + tid * 8] = s;
    }
  }
}

// ---------------- gate+up grouped GEMM (BM=128 BN=64x2 BK=64, pipelined) ----
// grid: (352, 16), block 256. x = e*44+nt  (352%8==0 -> m-tile siblings share XCD)
__global__ __launch_bounds__(256, 2) void gateup_kernel(
    const short* __restrict__ xg, const float* __restrict__ gate_w,
    const float* __restrict__ up_w, const int* __restrict__ bases,
    short* __restrict__ m_out) {
  const int bx = blockIdx.x;
  const int e = bx / 44, nt = bx - e * 44;
  const int b0 = bases[e];
  const int ne = bases[e + 1] - b0;
  const int row0 = blockIdx.y * 128;
  if (row0 >= ne) return;
  const int n0 = nt * 64;

  __shared__ short As[2][8192];      // [buf][sub*4096 + p*64 + j*8]
  __shared__ short Bs[2][2][4096];   // [buf][mat][sub*2048 + pn*64 + j*8]

  const int tid = threadIdx.x;
  const int lane = tid & 63, wid = tid >> 6;
  const int l31 = lane & 31, l5 = lane >> 5;
  const int wm = wid >> 1, wn = wid & 1;

  // A glds sources: 4 chunks/thread, pair-line xor folded into source addr
  const short* asrc[4];
#pragma unroll
  for (int q = 0; q < 4; q++) {
    int i = q * 256 + tid;
    int sub = i >> 9, ci = i & 511;
    int p = ci >> 3, j = ci & 7;
    int v = j ^ (p & 7);
    int r = 2 * p + (v >> 2), c = v & 3;
    int slot = b0 + imin(row0 + r, ne - 1);
    asrc[q] = xg + (size_t)slot * HD + sub * 32 + c * 8;
  }

  // B register staging: mat per wave-pair; f32x4, 256B-coalesced along n
  const int mat = tid >> 7;
  const int rb = tid & 127;
  const int fp2 = rb & 15, kq2 = rb >> 4;   // 16 f-quads x 8 k-octets
  const float* wsel = (mat ? up_w : gate_w) + (size_t)e * HD * FD + n0 + fp2 * 4;

  f32x16 accG[2], accU[2];
#pragma unroll
  for (int fm = 0; fm < 2; fm++) { accG[fm] = (f32x16)0.f; accU[fm] = (f32x16)0.f; }

  f32x4 bvA[8], bvB[8];

  auto stageA = [&](int buf, int k0) {
#pragma unroll
    for (int q = 0; q < 4; q++)
      glds16(asrc[q] + k0, &As[buf][(q * 256 + wid * 64) * 8]);
  };
  auto loadB = [&](f32x4 (&bv)[8], int k0) {
#pragma unroll
    for (int i = 0; i < 8; i++)
      bv[i] = *(const f32x4*)(wsel + (size_t)(k0 + kq2 * 8 + i) * FD);
  };
  auto writeB = [&](int buf, f32x4 (&bv)[8]) {
    short* Bd = &Bs[buf][mat][0];
    const int sub = kq2 >> 2, c = kq2 & 3;
#pragma unroll
    for (int ff = 0; ff < 4; ff++) {
      int fl = fp2 * 4 + ff, p = fl >> 1;
      int j = (((fl & 1) << 2) | c) ^ (p & 7);
      short8 s;
#pragma unroll
      for (int i = 0; i < 8; i++) s[i] = f2bf(bv[i][ff]);
      *(short8*)&Bd[sub * 2048 + p * 64 + j * 8] = s;
    }
  };
  auto mfma_on = [&](int cur) {
#pragma unroll
    for (int ks = 0; ks < 4; ks++) {
      const int sub = ks >> 1, chi = (ks & 1) * 2 + l5;
      short8 a[2], bg, bu;
#pragma unroll
      for (int fm = 0; fm < 2; fm++) {
        int r = wm * 64 + fm * 32 + l31;
        int p = r >> 1;
        a[fm] = *(const short8*)&As[cur][sub * 4096 + p * 64 +
                  ((((r & 1) << 2) | chi) ^ (p & 7)) * 8];
      }
      int n = wn * 32 + l31, pn = n >> 1;
      int off = sub * 2048 + pn * 64 + ((((n & 1) << 2) | chi) ^ (pn & 7)) * 8;
      bg = *(const short8*)&Bs[cur][0][off];
      bu = *(const short8*)&Bs[cur][1][off];
#pragma unroll
      for (int fm = 0; fm < 2; fm++) {
        accG[fm] = __builtin_amdgcn_mfma_f32_32x32x16_bf16(a[fm], bg, accG[fm], 0, 0, 0);
        accU[fm] = __builtin_amdgcn_mfma_f32_32x32x16_bf16(a[fm], bu, accU[fm], 0, 0, 0);
      }
    }
  };

  // prologue: tile0 in As[0]/Bs[0]; tile1 A-glds issued, B-tile1 in bvA
  stageA(0, 0);
  loadB(bvA, 0);
  stageA(1, 64);
  writeB(0, bvA);        // compiler waits bvA vmcnt
  loadB(bvA, 64);
  WAITV(12);             // A(0) landed; A(1)+B(1)-regs may fly
  BARRIER();

  // main loop: NTL=16 tiles, 7 unrolled pairs (t = 0..13)
  for (int tp = 0; tp < 14; tp += 2) {
    loadB(bvB, (tp + 2) * 64);
    mfma_on(0);
    writeB(1, bvA);
    WAITV(8);            // A(t+1) landed; B(t+2) flying
    BARRIER();
    stageA(0, (tp + 2) * 64);

    loadB(bvA, (tp + 3) * 64);
    mfma_on(1);
    writeB(0, bvB);
    WAITV(8);
    BARRIER();
    stageA(1, (tp + 3) * 64);
  }
  // t=14
  mfma_on(0);
  writeB(1, bvA);
  WAITV(0);
  BARRIER();
  // t=15
  mfma_on(1);

#pragma unroll
  for (int fm = 0; fm < 2; fm++)
#pragma unroll
    for (int q = 0; q < 16; q++) {
      int r = row0 + wm * 64 + fm * 32 + (q & 3) + 8 * (q >> 2) + 4 * l5;
      if (r < ne) {
        int slot = b0 + r;
        float g = accG[fm][q], u = accU[fm][q];
        float mv = (g / (1.f + __expf(-g))) * u;
        m_out[(size_t)slot * FD + n0 + wn * 32 + l31] = f2bf(mv);
      }
    }
}

// ---------------- down grouped GEMM (BM=64 BN=64 BK=64, all-glds, 3-buf) ----
// grid: (128, 32), block 256. x = e*16+nt  (128%8==0 -> m-siblings share XCD)
__global__ __launch_bounds__(256, 3) void down_kernel(
    const short* __restrict__ m_in, const short* __restrict__ Pd,
    const int* __restrict__ bases, const float* __restrict__ slot_w,
    float* __restrict__ out_slot) {
  const int bx = blockIdx.x;
  const int e = bx >> 4, nt = bx & 15;
  const int b0 = bases[e];
  const int ne = bases[e + 1] - b0;
  const int row0 = blockIdx.y * 64;
  if (row0 >= ne) return;

  __shared__ short As[3][4096];
  __shared__ short Bs[3][4096];

  const int tid = threadIdx.x;
  const int lane = tid & 63, wid = tid >> 6;
  const int l31 = lane & 31, l5 = lane >> 5;
  const int wm = wid >> 1, wn = wid & 1;

  const short* asrc[2];
#pragma unroll
  for (int q = 0; q < 2; q++) {
    int i = q * 256 + tid;
    int sub = i >> 8, ci = i & 255;
    int p = ci >> 3, j = ci & 7;
    int v = j ^ (p & 7);
    int r = 2 * p + (v >> 2), c = v & 3;
    int slot = b0 + imin(row0 + r, ne - 1);
    asrc[q] = m_in + (size_t)slot * FD + sub * 32 + c * 8;
  }
  const short* bbase = Pd + (size_t)e * NKT * 32768 + (size_t)nt * 2048;

  f32x16 acc = (f32x16)0.f;

  auto stage = [&](short* Ab, short* Bb, int t2) {
    const int k0 = t2 * 64, kt0 = t2 * 2;
#pragma unroll
    for (int q = 0; q < 2; q++) {
      int i = q * 256 + tid;
      int sub = i >> 8, ci = i & 255;
      glds16(asrc[q] + k0, Ab + i * 8);
      glds16(bbase + (size_t)(kt0 + sub) * 32768 + ci * 8, Bb + i * 8);
    }
  };
  auto compute = [&](const short* Ab, const short* Bb) {
#pragma unroll
    for (int ks = 0; ks < 4; ks++) {
      const int sub = ks >> 1, chi = (ks & 1) * 2 + l5;
      int r = wm * 32 + l31, p = r >> 1;
      short8 a = *(const short8*)(Ab + sub * 2048 + p * 64 +
                  ((((r & 1) << 2) | chi) ^ (p & 7)) * 8);
      int n = wn * 32 + l31, pn = n >> 1;
      short8 b = *(const short8*)(Bb + sub * 2048 + pn * 64 +
                  ((((n & 1) << 2) | chi) ^ (pn & 7)) * 8);
      acc = __builtin_amdgcn_mfma_f32_32x32x16_bf16(a, b, acc, 0, 0, 0);
    }
  };

  const int NTL = FD / 64;   // 44
  short *a0 = As[0], *a1 = As[1], *a2 = As[2];
  short *bb0 = Bs[0], *bb1 = Bs[1], *bb2 = Bs[2];

  stage(a0, bb0, 0);
  stage(a1, bb1, 1);
  WAITV(4);
  BARRIER();

  for (int t = 0; t < NTL - 2; ++t) {
    stage(a2, bb2, t + 2);   // issue-first: ~2 bodies of latency cover
    compute(a0, bb0);
    WAITV(4);                // tile t+1 landed; t+2 flying
    BARRIER();
    short* ta = a0; a0 = a1; a1 = a2; a2 = ta;
    short* tb = bb0; bb0 = bb1; bb1 = bb2; bb2 = tb;
  }
  compute(a0, bb0);
  WAITV(0);
  BARRIER();
  compute(a1, bb1);

#pragma unroll
  for (int q = 0; q < 16; q++) {
    int r = row0 + wm * 32 + (q & 3) + 8 * (q >> 2) + 4 * l5;
    if (r < ne) {
      int slot = b0 + r;
      out_slot[(size_t)slot * HD + nt * 64 + wn * 32 + l31] = acc[q] * slot_w[slot];
    }
  }
}

// ---------------- combine ---------------------------------------------------
__global__ void combine_kernel(const float* __restrict__ out_slot,
                               const int* __restrict__ slot_of,
                               float* __restrict__ out) {
  const int t = blockIdx.x;
  const int s0 = slot_of[t * 2];
  const int s1 = slot_of[t * 2 + 1];
  const int i = threadIdx.x * 4;
  f32x4 a = *(const f32x4*)(out_slot + (size_t)s0 * HD + i);
  f32x4 b = *(const f32x4*)(out_slot + (size_t)s1 * HD + i);
  f32x4 c = a + b;
  *(f32x4*)(out + (size_t)t * HD + i) = c;
}

extern "C" void kernel_launch(void* const* d_in, const int* in_sizes, int n_in,
                              void* d_out, int out_size, void* d_ws,
                              size_t ws_size, hipStream_t stream) {
  const float* x = (const float*)d_in[0];
  const float* rw = (const float*)d_in[1];
  const float* gw = (const float*)d_in[2];
  const float* uw = (const float*)d_in[3];
  const float* dw = (const float*)d_in[4];
  float* out = (float*)d_out;

  char* ws = (char*)d_ws;
  int* counts = (int*)(ws + 0);
  int* cursor = (int*)(ws + 64);
  int* bases = (int*)(ws + 128);
  int* tok_i = (int*)(ws + 256);
  float* tok_w = (float*)(ws + 8448);
  int* slot_token = (int*)(ws + 16640);
  float* slot_w = (float*)(ws + 24832);
  int* slot_of = (int*)(ws + 33024);
  short* xg = (short*)(ws + 41216);             // 2048 x 1024 bf16
  short* m_buf = (short*)(ws + 4235520);        // 2048 x 2816 bf16
  float* out_slot = (float*)(ws + 15769856);    // 2048 x 1024 f32
  short* Pd = (short*)(ws + 24158464);          // packed down_w bf16, 46.1 MB

  hipMemsetAsync(counts, 0, 64, stream);
  router_kernel<<<NT, 64, 0, stream>>>(x, rw, counts, tok_i, tok_w);
  scan_kernel<<<1, 64, 0, stream>>>(counts, bases, cursor);
  fill_kernel<<<NT / 256, 256, 0, stream>>>(tok_i, tok_w, cursor, slot_token,
                                            slot_w, slot_of);
  gather_kernel<<<NSLOT, 256, 0, stream>>>(x, slot_token, xg);
  pack_down_kernel<<<dim3(NKT, NE), 256, 0, stream>>>(dw, Pd);
  gateup_kernel<<<dim3(352, 16), 256, 0, stream>>>(xg, gw, uw, bases, m_buf);
  down_kernel<<<dim3(128, 32), 256, 0, stream>>>(m_buf, Pd, bases, slot_w,
                                                 out_slot);
  combine_kernel<<<NT, 256, 0, stream>>>(out_slot, slot_of, out);
}